// Round 3
// baseline (147.827 us; speedup 1.0000x reference)
//
#include <hip/hip_runtime.h>
#include <hip/hip_bf16.h>

typedef __bf16 bf16x8 __attribute__((ext_vector_type(8)));
typedef float  f32x4  __attribute__((ext_vector_type(4)));

#define LOG2E 1.4426950408889634f

__device__ __forceinline__ float lrelu(float x) { return x >= 0.f ? x : 0.2f * x; }

__device__ __forceinline__ float exp2f_fast(float x) {
#if __has_builtin(__builtin_amdgcn_exp2f)
    return __builtin_amdgcn_exp2f(x);
#else
    return __expf(x * 0.6931471805599453f);
#endif
}

__device__ __forceinline__ unsigned short bfbits(float x) {
    __hip_bfloat16 h = __float2bfloat16(x);
    return *reinterpret_cast<unsigned short*>(&h);
}

// pack E1=exp2(d) in high 16, E2=exp2(0.2d) in low 16
__device__ __forceinline__ unsigned packE(float d) {
    const unsigned b1 = bfbits(exp2f_fast(d));
    const unsigned b2 = bfbits(exp2f_fast(0.2f * d));
    return (b1 << 16) | b2;
}

// -------- kernel 1: h_prime GEMM; src/dst (scaled by log2e); hpF frag-permuted bf16 --------
__global__ __launch_bounds__(256) void k_hprime(
    const float* __restrict__ hg,     // [8,2048,64]
    const float* __restrict__ wg,     // [4,64,32]
    const float* __restrict__ a_src,  // [4,32]
    const float* __restrict__ a_dst,  // [4,32]
    __hip_bfloat16* __restrict__ hpF, // [32][32][2048] bf16, k-permuted per 32-block
    float* __restrict__ srcv,         // [32][2048]  (x log2e)
    float* __restrict__ dstv)         // [32][2048]  (x log2e)
{
    __shared__ float w_lds[64 * 32];
    __shared__ float h_lds[64 * 64];
    __shared__ __hip_bfloat16 t_lds[32 * 72];

    const int t  = threadIdx.x;
    const int bh = blockIdx.x >> 5;
    const int n0 = (blockIdx.x & 31) * 64;
    const int b  = bh >> 2, hh = bh & 3;

    {
        const float4* s4 = (const float4*)(wg + hh * 2048);
        float4* d4 = (float4*)w_lds;
        d4[t] = s4[t];
        d4[t + 256] = s4[t + 256];
        const float4* s4h = (const float4*)(hg + ((size_t)(b * 2048 + n0)) * 64);
        float4* d4h = (float4*)h_lds;
#pragma unroll
        for (int k = 0; k < 4; k++) d4h[t + 256 * k] = s4h[t + 256 * k];
    }
    __syncthreads();

    const int o  = t & 31;
    const int nb = t >> 5;
    float acc[8];
#pragma unroll
    for (int k = 0; k < 8; k++) acc[k] = 0.f;
    for (int f = 0; f < 64; f++) {
        const float wv = w_lds[f * 32 + o];
#pragma unroll
        for (int k = 0; k < 8; k++)
            acc[k] = fmaf(h_lds[(nb + 8 * k) * 64 + f], wv, acc[k]);
    }
    const float as = a_src[hh * 32 + o] * LOG2E;
    const float ad = a_dst[hh * 32 + o] * LOG2E;
#pragma unroll
    for (int k = 0; k < 8; k++) {
        float sv = acc[k] * as;
        float dv = acc[k] * ad;
#pragma unroll
        for (int m = 16; m >= 1; m >>= 1) {
            sv += __shfl_xor(sv, m);
            dv += __shfl_xor(dv, m);
        }
        if (o == 0) {
            const int n = n0 + nb + 8 * k;
            srcv[bh * 2048 + n] = sv;
            dstv[bh * 2048 + n] = dv;
        }
    }
#pragma unroll
    for (int k = 0; k < 8; k++)
        t_lds[o * 72 + nb + 8 * k] = __float2bfloat16(acc[k]);
    __syncthreads();
    {
        // write frag-permuted: within each 32-j block, position g*8+e holds
        // j = 4g+e (e<4) / 16+4g+(e-4) (e>=4)
        const int oo = t >> 3;       // 0..31
        const int ch = t & 7;        // 0..7 : jb=ch>>2, g=ch&3
        const int jb = ch >> 2, g = ch & 3;
        const __hip_bfloat16* src0 = &t_lds[oo * 72 + jb * 32 + g * 4];
        union { unsigned long long q[2]; uint4 v; } u;
        u.q[0] = *(const unsigned long long*)(src0);
        u.q[1] = *(const unsigned long long*)(src0 + 16);
        *(uint4*)(hpF + ((size_t)(bh * 32 + oo)) * 2048 + n0 + ch * 8) = u.v;
    }
}

// -------- kernel 2: role-split. even blocks: stream attn writes (no barriers in loop).
//          odd blocks: MFMA PV -> output. Both: E-table prepass. --------
__global__ __launch_bounds__(256) void k_main(
    const __hip_bfloat16* __restrict__ hpF,
    const float* __restrict__ srcv,
    const float* __restrict__ dstv,
    const float* __restrict__ bias,
    float* __restrict__ outp,   // [32][2048][32]
    float* __restrict__ attn)   // [32][2048][2048]
{
    __shared__ __attribute__((aligned(16))) float    d_lds[2048];
    __shared__ __attribute__((aligned(16))) unsigned e12[2048];
    __shared__ float ns_lds[64], a1_lds[64], a2_lds[64];
    __shared__ float red[4];

    const int t    = threadIdx.x;
    const int role = blockIdx.x & 1;
    const int wid  = blockIdx.x >> 1;
    const int bh   = wid >> 5;
    const int row0 = (wid & 31) * 64;

    // stage d + block max
    float lmax = -1e30f;
    {
        const float4* s4 = (const float4*)(dstv + bh * 2048);
        float4* d4 = (float4*)d_lds;
#pragma unroll
        for (int k = 0; k < 2; k++) {
            const float4 v = s4[t + 256 * k];
            d4[t + 256 * k] = v;
            lmax = fmaxf(lmax, fmaxf(fmaxf(v.x, v.y), fmaxf(v.z, v.w)));
        }
    }
#pragma unroll
    for (int m = 32; m >= 1; m >>= 1) lmax = fmaxf(lmax, __shfl_xor(lmax, m));
    if ((t & 63) == 0) red[t >> 6] = lmax;
    __syncthreads();
    const float dmax = fmaxf(fmaxf(red[0], red[1]), fmaxf(red[2], red[3]));

    // fill E tables
    {
#pragma unroll
        for (int k = 0; k < 2; k++) {
            const float4 dv = *((const float4*)d_lds + t + 256 * k);
            uint4 u;
            u.x = packE(dv.x); u.y = packE(dv.y);
            u.z = packE(dv.z); u.w = packE(dv.w);
            *((uint4*)e12 + t + 256 * k) = u;
        }
    }
    __syncthreads();

    // prepass: per-row -s, a1 = exp2(s-m)/sum, a2 = exp2(0.2s-m)/sum
    {
        const int r = t >> 2, q = t & 3;
        const float s  = srcv[bh * 2048 + row0 + r];
        const float ns = -s;
        float acc1 = 0.f, acc2 = 0.f;
        for (int it = 0; it < 128; it++) {
            const int j = q * 4 + it * 16;
            const float4 dv = *(const float4*)(d_lds + j);
            const uint4  uv = *(const uint4*)(e12 + j);
            { const bool c = dv.x >= ns; acc1 += c ? __uint_as_float(uv.x & 0xffff0000u) : 0.f; acc2 += c ? 0.f : __uint_as_float(uv.x << 16); }
            { const bool c = dv.y >= ns; acc1 += c ? __uint_as_float(uv.y & 0xffff0000u) : 0.f; acc2 += c ? 0.f : __uint_as_float(uv.y << 16); }
            { const bool c = dv.z >= ns; acc1 += c ? __uint_as_float(uv.z & 0xffff0000u) : 0.f; acc2 += c ? 0.f : __uint_as_float(uv.z << 16); }
            { const bool c = dv.w >= ns; acc1 += c ? __uint_as_float(uv.w & 0xffff0000u) : 0.f; acc2 += c ? 0.f : __uint_as_float(uv.w << 16); }
        }
        acc1 += __shfl_xor(acc1, 1); acc1 += __shfl_xor(acc1, 2);
        acc2 += __shfl_xor(acc2, 1); acc2 += __shfl_xor(acc2, 2);
        if (q == 0) {
            const float m  = lrelu(s + dmax);
            const float f1 = exp2f_fast(s - m);
            const float f2 = exp2f_fast(0.2f * s - m);
            const float is = 1.f / (f1 * acc1 + f2 * acc2);
            ns_lds[r] = ns; a1_lds[r] = f1 * is; a2_lds[r] = f2 * is;
        }
    }
    __syncthreads();

    if (role == 0) {
        // ---- writer: stream 64 rows x 2048 f32, no barriers ----
        float* rowbase = attn + ((size_t)(bh * 2048) + row0) * 2048;
        for (int r = 0; r < 64; r++) {
            const float ns = ns_lds[r], a1 = a1_lds[r], a2 = a2_lds[r];
            float* rp = rowbase + (size_t)r * 2048;
#pragma unroll
            for (int h2 = 0; h2 < 2; h2++) {
                const int j = t * 4 + h2 * 1024;
                const float4 dv = *(const float4*)(d_lds + j);
                const uint4  uv = *(const uint4*)(e12 + j);
                f32x4 p;
                { const bool c = dv.x >= ns; p[0] = (c ? a1 : a2) * __uint_as_float(c ? (uv.x & 0xffff0000u) : (uv.x << 16)); }
                { const bool c = dv.y >= ns; p[1] = (c ? a1 : a2) * __uint_as_float(c ? (uv.y & 0xffff0000u) : (uv.y << 16)); }
                { const bool c = dv.z >= ns; p[2] = (c ? a1 : a2) * __uint_as_float(c ? (uv.z & 0xffff0000u) : (uv.z << 16)); }
                { const bool c = dv.w >= ns; p[3] = (c ? a1 : a2) * __uint_as_float(c ? (uv.w & 0xffff0000u) : (uv.w << 16)); }
                __builtin_nontemporal_store(p, (f32x4*)(rp + j));
            }
        }
    } else {
        // ---- PV: registers-only MFMA, no barriers in j-loop ----
        const int l  = t & 63, w = t >> 6;
        const int lr = l & 15, g = l >> 4;
        const int rA = w * 16 + lr;
        const float ns = ns_lds[rA], a1 = a1_lds[rA], a2 = a2_lds[rA];
        const __hip_bfloat16* hb0 = hpF + ((size_t)(bh * 32 + lr)) * 2048;
        const __hip_bfloat16* hb1 = hpF + ((size_t)(bh * 32 + 16 + lr)) * 2048;
        f32x4 acc0 = {0.f, 0.f, 0.f, 0.f};
        f32x4 acc1v = {0.f, 0.f, 0.f, 0.f};
        for (int jb = 0; jb < 64; jb++) {
            const int j = jb * 32 + g * 4;
            const float4 dA = *(const float4*)(d_lds + j);
            const float4 dB = *(const float4*)(d_lds + j + 16);
            const uint4  uA = *(const uint4*)(e12 + j);
            const uint4  uB = *(const uint4*)(e12 + j + 16);
            union { unsigned short us[8]; bf16x8 v; } A;
            { const bool c = dA.x >= ns; A.us[0] = bfbits((c ? a1 : a2) * __uint_as_float(c ? (uA.x & 0xffff0000u) : (uA.x << 16))); }
            { const bool c = dA.y >= ns; A.us[1] = bfbits((c ? a1 : a2) * __uint_as_float(c ? (uA.y & 0xffff0000u) : (uA.y << 16))); }
            { const bool c = dA.z >= ns; A.us[2] = bfbits((c ? a1 : a2) * __uint_as_float(c ? (uA.z & 0xffff0000u) : (uA.z << 16))); }
            { const bool c = dA.w >= ns; A.us[3] = bfbits((c ? a1 : a2) * __uint_as_float(c ? (uA.w & 0xffff0000u) : (uA.w << 16))); }
            { const bool c = dB.x >= ns; A.us[4] = bfbits((c ? a1 : a2) * __uint_as_float(c ? (uB.x & 0xffff0000u) : (uB.x << 16))); }
            { const bool c = dB.y >= ns; A.us[5] = bfbits((c ? a1 : a2) * __uint_as_float(c ? (uB.y & 0xffff0000u) : (uB.y << 16))); }
            { const bool c = dB.z >= ns; A.us[6] = bfbits((c ? a1 : a2) * __uint_as_float(c ? (uB.z & 0xffff0000u) : (uB.z << 16))); }
            { const bool c = dB.w >= ns; A.us[7] = bfbits((c ? a1 : a2) * __uint_as_float(c ? (uB.w & 0xffff0000u) : (uB.w << 16))); }
            const bf16x8 b0 = *(const bf16x8*)(hb0 + jb * 32 + g * 8);
            const bf16x8 b1 = *(const bf16x8*)(hb1 + jb * 32 + g * 8);
            acc0  = __builtin_amdgcn_mfma_f32_16x16x32_bf16(A.v, b0, acc0, 0, 0, 0);
            acc1v = __builtin_amdgcn_mfma_f32_16x16x32_bf16(A.v, b1, acc1v, 0, 0, 0);
        }
        const float b0v = bias[lr];
        const float b1v = bias[16 + lr];
#pragma unroll
        for (int reg = 0; reg < 4; reg++) {
            const int grow = row0 + w * 16 + g * 4 + reg;
            float* op = outp + ((size_t)(bh * 2048) + grow) * 32;
            op[lr]      = acc0[reg] + b0v;
            op[16 + lr] = acc1v[reg] + b1v;
        }
    }
}

extern "C" void kernel_launch(void* const* d_in, const int* in_sizes, int n_in,
                              void* d_out, int out_size, void* d_ws, size_t ws_size,
                              hipStream_t stream) {
    (void)in_sizes; (void)n_in; (void)out_size; (void)ws_size;
    const float* h     = (const float*)d_in[0];
    const float* w     = (const float*)d_in[1];
    const float* a_src = (const float*)d_in[2];
    const float* a_dst = (const float*)d_in[3];
    const float* b     = (const float*)d_in[4];

    float* out  = (float*)d_out;
    float* attn = out + (size_t)8 * 4 * 2048 * 32;

    __hip_bfloat16* hpF = (__hip_bfloat16*)d_ws;                        // 4 MB
    float* srcv = (float*)((char*)d_ws + (size_t)32 * 32 * 2048 * 2);   // 256 KB
    float* dstv = srcv + 32 * 2048;                                     // 256 KB

    k_hprime<<<1024, 256, 0, stream>>>(h, w, a_src, a_dst, hpF, srcv, dstv);
    k_main  <<<2048, 256, 0, stream>>>(hpF, srcv, dstv, b, out, attn);
}